// Round 3
// baseline (1173.572 us; speedup 1.0000x reference)
//
#include <hip/hip_runtime.h>

#define N_IN 128
#define HID 256
#define NB 16
#define BM 64
#define HS_STRIDE 264   // 256 + 8 bf16 pad -> phase-C A reads avoid pow2 bank aliasing
#define BS_STRIDE 17    // basis LDS stride (f32)

typedef __attribute__((ext_vector_type(8))) short s8v;   // 8 bf16 in 4 VGPRs
typedef __attribute__((ext_vector_type(4))) float f4v;   // MFMA 16x16x32 accumulator

__device__ __forceinline__ unsigned short f2bf(float f) {
  unsigned int u = __float_as_uint(f);
  u += 0x7fffu + ((u >> 16) & 1u);   // round-to-nearest-even
  return (unsigned short)(u >> 16);
}

__device__ __forceinline__ float tanh_fast(float x) {
  float e = __expf(2.0f * x);
  return 1.0f - 2.0f * __builtin_amdgcn_rcpf(e + 1.0f);
}

// Repack weights to bf16 in MFMA *fragment order*: each fragment is 64 lanes x 16 B
// contiguous (1 KB), so a B-operand load is one fully-coalesced global_load_dwordx4.
// Fragment element (lane, j):  B[n = l15][k = (lane>>4)*8 + j]  within the tile.
// W1f frag id (pass, kk, ct):  n = pass*128 + ct*16 + l15, k = kk*32 + quad*8 + j,  val = W1[k*256 + n]
// W2f frag id (b, kk, ct):     n = ct*16 + l15,  k = kk*32 + quad*8 + j,            val = W2[k*2048 + n*16 + b]
__global__ void prep_kernel(const float* __restrict__ W1, const float* __restrict__ W2,
                            unsigned short* __restrict__ W1f, unsigned short* __restrict__ W2f) {
  int tid = blockIdx.x * blockDim.x + threadIdx.x;
  if (tid < N_IN * HID) {                     // 32768 W1 elements
    int j = tid & 7, lane = (tid >> 3) & 63, ct = (tid >> 9) & 7, kk = (tid >> 12) & 3, pass = tid >> 14;
    int n = pass * 128 + ct * 16 + (lane & 15);
    int k = kk * 32 + (lane >> 4) * 8 + j;
    W1f[tid] = f2bf(W1[k * HID + n]);
  }
  int i = tid - N_IN * HID;
  if (i >= 0 && i < HID * (N_IN * NB)) {      // 524288 W2 elements
    int j = i & 7, lane = (i >> 3) & 63, ct = (i >> 9) & 7, kk = (i >> 12) & 7, b = i >> 15;
    int n = ct * 16 + (lane & 15);
    int k = kk * 32 + (lane >> 4) * 8 + j;
    W2f[i] = f2bf(W2[k * (N_IN * NB) + n * 16 + b]);
  }
}

__global__ void __launch_bounds__(256, 4)
pilayer_kernel(const float* __restrict__ prop,
               const int* __restrict__ idx_i,
               const int* __restrict__ idx_j,
               const float* __restrict__ basis,
               const unsigned short* __restrict__ W1f,
               const unsigned short* __restrict__ W2f,
               float* __restrict__ out, int P) {
  __shared__ unsigned short Hs[BM * HS_STRIDE];   // 33,792 B
  __shared__ float basisS[BM * BS_STRIDE];        //  4,352 B  -> 38.1 KB, 4 blocks/CU

  const int t = threadIdx.x;
  const int lane = t & 63;
  const int wv = t >> 6;
  const int l15 = lane & 15;
  const int l4 = lane >> 4;
  const int tile0 = blockIdx.x * BM;

  // ---- stage basis tile cooperatively (64 rows x 16 f32, 4 f32/thread) ----
  {
    int r = t >> 2;                 // 0..63
    int c0 = (t & 3) * 4;
    int p = tile0 + r; if (p >= P) p = P - 1;
    float4 b0 = *(const float4*)(basis + (long)p * NB + c0);
    float* dst = &basisS[r * BS_STRIDE + c0];
    dst[0] = b0.x; dst[1] = b0.y; dst[2] = b0.z; dst[3] = b0.w;
  }

  // ---- Phase B: wave wv computes H rows [16*wv, 16*wv+16), all 256 cols ----
  {
    const int row0 = wv * 16;
    int p = tile0 + row0 + l15; if (p >= P) p = P - 1;
    const int pi = idx_i[p];
    const int qi = idx_j[p];
#pragma unroll
    for (int pass = 0; pass < 2; ++pass) {
      f4v acc[8];
#pragma unroll
      for (int ct = 0; ct < 8; ++ct) acc[ct] = (f4v){0.f, 0.f, 0.f, 0.f};
#pragma unroll
      for (int kk = 0; kk < 4; ++kk) {        // K = 128, step 32
        int k0 = kk * 32 + l4 * 8;
        const float4* ai = (const float4*)(prop + (long)pi * N_IN + k0);
        const float4* aj = (const float4*)(prop + (long)qi * N_IN + k0);
        float4 x0 = ai[0], x1 = ai[1];
        float4 y0 = aj[0], y1 = aj[1];
        s8v afr;
        afr[0] = (short)f2bf(x0.x + y0.x); afr[1] = (short)f2bf(x0.y + y0.y);
        afr[2] = (short)f2bf(x0.z + y0.z); afr[3] = (short)f2bf(x0.w + y0.w);
        afr[4] = (short)f2bf(x1.x + y1.x); afr[5] = (short)f2bf(x1.y + y1.y);
        afr[6] = (short)f2bf(x1.z + y1.z); afr[7] = (short)f2bf(x1.w + y1.w);
#pragma unroll
        for (int ct = 0; ct < 8; ++ct) {
          s8v bfr = *(const s8v*)(W1f + ((((pass * 4 + kk) * 8 + ct) * 64 + lane) << 3));
          acc[ct] = __builtin_amdgcn_mfma_f32_16x16x32_bf16(afr, bfr, acc[ct], 0, 0, 0);
        }
      }
#pragma unroll
      for (int ct = 0; ct < 8; ++ct)
#pragma unroll
        for (int r = 0; r < 4; ++r) {
          int lrow = row0 + l4 * 4 + r;
          int col = pass * 128 + ct * 16 + l15;
          Hs[lrow * HS_STRIDE + col] = f2bf(tanh_fast(acc[ct][r]));
        }
    }
  }

  __syncthreads();   // H + basis visible to all waves

  // ---- Phase C: column split — wave wv owns cols [wv*32, wv*32+32), all 64 rows ----
  const int cq = wv * 2;             // col-tile offset (x16 cols)

  f4v oacc[4][2];
#pragma unroll
  for (int rt = 0; rt < 4; ++rt)
#pragma unroll
    for (int ct = 0; ct < 2; ++ct) oacc[rt][ct] = (f4v){0.f, 0.f, 0.f, 0.f};

#pragma unroll 1
  for (int b = 0; b < NB; ++b) {
    f4v g[4][2];
#pragma unroll
    for (int rt = 0; rt < 4; ++rt)
#pragma unroll
      for (int ct = 0; ct < 2; ++ct) g[rt][ct] = (f4v){0.f, 0.f, 0.f, 0.f};
#pragma unroll
    for (int kk = 0; kk < 8; ++kk) {          // K = 256, step 32
      s8v afr[4];
#pragma unroll
      for (int rt = 0; rt < 4; ++rt)
        afr[rt] = *(const s8v*)&Hs[(rt * 16 + l15) * HS_STRIDE + kk * 32 + l4 * 8];
      s8v bfr[2];
#pragma unroll
      for (int ct = 0; ct < 2; ++ct)
        bfr[ct] = *(const s8v*)(W2f + ((((b * 8 + kk) * 8 + cq + ct) * 64 + lane) << 3));
#pragma unroll
      for (int rt = 0; rt < 4; ++rt)
#pragma unroll
        for (int ct = 0; ct < 2; ++ct)
          g[rt][ct] = __builtin_amdgcn_mfma_f32_16x16x32_bf16(afr[rt], bfr[ct], g[rt][ct], 0, 0, 0);
    }
    // scale rows by basis[p][b], accumulate (C layout: row = l4*4 + reg within 16-tile)
#pragma unroll
    for (int rt = 0; rt < 4; ++rt)
#pragma unroll
      for (int r = 0; r < 4; ++r) {
        float bs = basisS[(rt * 16 + l4 * 4 + r) * BS_STRIDE + b];
#pragma unroll
        for (int ct = 0; ct < 2; ++ct)
          oacc[rt][ct][r] += g[rt][ct][r] * bs;
      }
  }

  // ---- epilogue: out[p][c], c = (cq+ct)*16 + l15 ----
#pragma unroll
  for (int rt = 0; rt < 4; ++rt)
#pragma unroll
    for (int r = 0; r < 4; ++r) {
      int p = tile0 + rt * 16 + l4 * 4 + r;
      if (p < P) {
        float* op = out + (long)p * N_IN + cq * 16 + l15;
#pragma unroll
        for (int ct = 0; ct < 2; ++ct)
          op[ct * 16] = oacc[rt][ct][r];
      }
    }
}

extern "C" void kernel_launch(void* const* d_in, const int* in_sizes, int n_in,
                              void* d_out, int out_size, void* d_ws, size_t ws_size,
                              hipStream_t stream) {
  const float* prop  = (const float*)d_in[0];
  const int* idx_i   = (const int*)d_in[1];
  const int* idx_j   = (const int*)d_in[2];
  const float* basis = (const float*)d_in[3];
  const float* W1    = (const float*)d_in[4];
  const float* W2    = (const float*)d_in[5];
  float* out = (float*)d_out;
  int P = in_sizes[1];

  unsigned short* W1f = (unsigned short*)d_ws;                 // 32768 bf16
  unsigned short* W2f = W1f + N_IN * HID;                      // 524288 bf16

  int prep_threads = N_IN * HID + HID * N_IN * NB;             // 557056
  prep_kernel<<<(prep_threads + 255) / 256, 256, 0, stream>>>(W1, W2, W1f, W2f);

  int ntiles = (P + BM - 1) / BM;
  pilayer_kernel<<<ntiles, 256, 0, stream>>>(prop, idx_i, idx_j, basis, W1f, W2f, out, P);
}

// Round 4
// 799.593 us; speedup vs baseline: 1.4677x; 1.4677x over previous
//
#include <hip/hip_runtime.h>

#define N_IN 128
#define HID 256
#define NB 16
#define BM 128
#define HS_STRIDE 264   // bf16 row stride for H tile (pad breaks pow2 bank aliasing)
#define BS_STRIDE 17    // basis LDS stride (f32)

typedef __attribute__((ext_vector_type(8))) short s8v;   // 8 bf16 = 4 VGPRs
typedef __attribute__((ext_vector_type(4))) float f4v;   // MFMA 16x16x32 accumulator
typedef __attribute__((address_space(3))) unsigned int as3_uint;
typedef const __attribute__((address_space(1))) unsigned int as1_uint;

__device__ __forceinline__ unsigned short f2bf(float f) {
  unsigned int u = __float_as_uint(f);
  u += 0x7fffu + ((u >> 16) & 1u);   // round-to-nearest-even
  return (unsigned short)(u >> 16);
}

__device__ __forceinline__ float tanh_fast(float x) {
  float e = __expf(2.0f * x);
  return 1.0f - 2.0f * __builtin_amdgcn_rcpf(e + 1.0f);
}

// Same fragment-ordered bf16 repack as round 2 (1 KB coalesced MFMA fragments).
// W1f frag (pass,kk,ct): n = pass*128+ct*16+l15, k = kk*32+quad*8+j, val = W1[k*256+n]
// W2f frag (b,kk,ct):    n = ct*16+l15,          k = kk*32+quad*8+j, val = W2[k*2048+n*16+b]
__global__ void prep_kernel(const float* __restrict__ W1, const float* __restrict__ W2,
                            unsigned short* __restrict__ W1f, unsigned short* __restrict__ W2f) {
  int tid = blockIdx.x * blockDim.x + threadIdx.x;
  if (tid < N_IN * HID) {
    int j = tid & 7, lane = (tid >> 3) & 63, ct = (tid >> 9) & 7, kk = (tid >> 12) & 3, pass = tid >> 14;
    int n = pass * 128 + ct * 16 + (lane & 15);
    int k = kk * 32 + (lane >> 4) * 8 + j;
    W1f[tid] = f2bf(W1[k * HID + n]);
  }
  int i = tid - N_IN * HID;
  if (i >= 0 && i < HID * (N_IN * NB)) {
    int j = i & 7, lane = (i >> 3) & 63, ct = (i >> 9) & 7, kk = (i >> 12) & 7, b = i >> 15;
    int n = ct * 16 + (lane & 15);
    int k = kk * 32 + (lane >> 4) * 8 + j;
    W2f[i] = f2bf(W2[k * (N_IN * NB) + n * 16 + b]);
  }
}

__global__ void __launch_bounds__(256, 2)
pilayer_kernel(const float* __restrict__ prop,
               const int* __restrict__ idx_i,
               const int* __restrict__ idx_j,
               const float* __restrict__ basis,
               const unsigned short* __restrict__ W1f,
               const unsigned short* __restrict__ W2f,
               float* __restrict__ out, int P) {
  __shared__ unsigned short Hs[BM * HS_STRIDE];   // 67,584 B; first 64 KB reused as B ping-pong
  __shared__ float basisS[BM * BS_STRIDE];        //  8,704 B  -> 76.3 KB, 2 blocks/CU

  const int t = threadIdx.x;
  const int lane = t & 63;
  const int wv = t >> 6;
  const int l15 = lane & 15;
  const int l4 = lane >> 4;
  const int tile0 = blockIdx.x * BM;
  const int r0 = wv * 32;           // this wave owns local rows [r0, r0+32) in B and C

  // ---- per-wave basis stage (own 32 rows -> no barrier needed) ----
  {
    int r = r0 + (lane >> 1);
    int c0 = (lane & 1) * 8;
    int p = tile0 + r; if (p >= P) p = P - 1;
    const float4* bp = (const float4*)(basis + (long)p * NB + c0);
    float4 b0 = bp[0], b1 = bp[1];
    float* dst = &basisS[r * BS_STRIDE + c0];
    dst[0] = b0.x; dst[1] = b0.y; dst[2] = b0.z; dst[3] = b0.w;
    dst[4] = b1.x; dst[5] = b1.y; dst[6] = b1.z; dst[7] = b1.w;
  }

  // ---- Phase B: wave computes H rows [r0, r0+32), all 256 cols (round-2 verified) ----
  {
    int pidx[2], qidx[2];
#pragma unroll
    for (int rt = 0; rt < 2; ++rt) {
      int p = tile0 + r0 + rt * 16 + l15; if (p >= P) p = P - 1;
      pidx[rt] = idx_i[p];
      qidx[rt] = idx_j[p];
    }
#pragma unroll
    for (int pass = 0; pass < 2; ++pass) {
      f4v acc[2][8];
#pragma unroll
      for (int rt = 0; rt < 2; ++rt)
#pragma unroll
        for (int ct = 0; ct < 8; ++ct) acc[rt][ct] = (f4v){0.f, 0.f, 0.f, 0.f};
#pragma unroll
      for (int kk = 0; kk < 4; ++kk) {
        int k0 = kk * 32 + l4 * 8;
        s8v afr[2];
#pragma unroll
        for (int rt = 0; rt < 2; ++rt) {
          const float4* ai = (const float4*)(prop + (long)pidx[rt] * N_IN + k0);
          const float4* aj = (const float4*)(prop + (long)qidx[rt] * N_IN + k0);
          float4 x0 = ai[0], x1 = ai[1];
          float4 y0 = aj[0], y1 = aj[1];
          s8v a;
          a[0] = (short)f2bf(x0.x + y0.x); a[1] = (short)f2bf(x0.y + y0.y);
          a[2] = (short)f2bf(x0.z + y0.z); a[3] = (short)f2bf(x0.w + y0.w);
          a[4] = (short)f2bf(x1.x + y1.x); a[5] = (short)f2bf(x1.y + y1.y);
          a[6] = (short)f2bf(x1.z + y1.z); a[7] = (short)f2bf(x1.w + y1.w);
          afr[rt] = a;
        }
#pragma unroll
        for (int ct = 0; ct < 8; ++ct) {
          s8v bfr = *(const s8v*)(W1f + ((((pass * 4 + kk) * 8 + ct) * 64 + lane) << 3));
#pragma unroll
          for (int rt = 0; rt < 2; ++rt)
            acc[rt][ct] = __builtin_amdgcn_mfma_f32_16x16x32_bf16(afr[rt], bfr, acc[rt][ct], 0, 0, 0);
        }
      }
#pragma unroll
      for (int rt = 0; rt < 2; ++rt)
#pragma unroll
        for (int ct = 0; ct < 8; ++ct)
#pragma unroll
          for (int r = 0; r < 4; ++r) {
            int lrow = r0 + rt * 16 + l4 * 4 + r;
            int col = pass * 128 + ct * 16 + l15;
            Hs[lrow * HS_STRIDE + col] = f2bf(tanh_fast(acc[rt][ct][r]));
          }
    }
  }

  // ---- A-cache: pull this wave's 16 A-fragments into registers (own rows -> wave-local order) ----
  s8v areg[2][8];
#pragma unroll
  for (int rt = 0; rt < 2; ++rt)
#pragma unroll
    for (int kk = 0; kk < 8; ++kk)
      areg[rt][kk] = *(const s8v*)&Hs[(r0 + rt * 16 + l15) * HS_STRIDE + kk * 32 + l4 * 8];

  __syncthreads();   // all waves done reading Hs; its space becomes B ping-pong

  unsigned short* Bb = Hs;   // 2 x 16384 shorts (32 KB) ping-pong for W2f slices

  // stage slice it = b*2 + cp (cols [cp*64, cp*64+64), all K): 32 x 1KB fragments, 8 per wave
  auto stage = [&](int it2) {
    unsigned short* dstbase = Bb + (it2 & 1) * 16384;
    int b = it2 >> 1, cp = it2 & 1;
#pragma unroll
    for (int i = 0; i < 8; ++i) {
      int s = wv * 8 + i;
      int kk = s >> 2, ctl = s & 3;
      const unsigned short* src = W2f + (((b * 8 + kk) * 8 + cp * 4 + ctl) << 9) + lane * 8;
      unsigned short* dst = dstbase + ((kk * 4 + ctl) << 9);   // HW adds lane*16B
      __builtin_amdgcn_global_load_lds((as1_uint*)src, (as3_uint*)dst, 16, 0, 0);
    }
  };

  stage(0);

  f4v o[2][8];
#pragma unroll
  for (int rt = 0; rt < 2; ++rt)
#pragma unroll
    for (int ct = 0; ct < 8; ++ct) o[rt][ct] = (f4v){0.f, 0.f, 0.f, 0.f};

#pragma unroll 1
  for (int it = 0; it < 32; ++it) {
    __syncthreads();              // drains vmcnt -> staged(it) visible; prior reads of other buf done
    if (it < 31) stage(it + 1);   // async fill of the other buffer during compute
    const int b = it >> 1, cp = it & 1;
    const unsigned short* buf = Bb + (it & 1) * 16384;

    float bs[2][4];
#pragma unroll
    for (int rt = 0; rt < 2; ++rt)
#pragma unroll
      for (int r = 0; r < 4; ++r)
        bs[rt][r] = basisS[(r0 + rt * 16 + l4 * 4 + r) * BS_STRIDE + b];

    f4v g[2][4];
#pragma unroll
    for (int rt = 0; rt < 2; ++rt)
#pragma unroll
      for (int ct = 0; ct < 4; ++ct) g[rt][ct] = (f4v){0.f, 0.f, 0.f, 0.f};

#pragma unroll
    for (int kk = 0; kk < 8; ++kk) {
      s8v bf[4];
#pragma unroll
      for (int ctl = 0; ctl < 4; ++ctl)
        bf[ctl] = *(const s8v*)&buf[((kk * 4 + ctl) << 9) + lane * 8];
#pragma unroll
      for (int rt = 0; rt < 2; ++rt)
#pragma unroll
        for (int ctl = 0; ctl < 4; ++ctl)
          g[rt][ctl] = __builtin_amdgcn_mfma_f32_16x16x32_bf16(areg[rt][kk], bf[ctl], g[rt][ctl], 0, 0, 0);
    }
#pragma unroll
    for (int rt = 0; rt < 2; ++rt)
#pragma unroll
      for (int ctl = 0; ctl < 4; ++ctl)
#pragma unroll
        for (int r = 0; r < 4; ++r)
          o[rt][cp * 4 + ctl][r] += g[rt][ctl][r] * bs[rt][r];
  }

  // ---- epilogue: out[p][c], c = ct*16 + l15 ----
#pragma unroll
  for (int rt = 0; rt < 2; ++rt)
#pragma unroll
    for (int r = 0; r < 4; ++r) {
      int p = tile0 + r0 + rt * 16 + l4 * 4 + r;
      if (p < P) {
        float* op = out + (long)p * N_IN + l15;
#pragma unroll
        for (int ct = 0; ct < 8; ++ct)
          op[ct * 16] = o[rt][ct][r];
      }
    }
}

extern "C" void kernel_launch(void* const* d_in, const int* in_sizes, int n_in,
                              void* d_out, int out_size, void* d_ws, size_t ws_size,
                              hipStream_t stream) {
  const float* prop  = (const float*)d_in[0];
  const int* idx_i   = (const int*)d_in[1];
  const int* idx_j   = (const int*)d_in[2];
  const float* basis = (const float*)d_in[3];
  const float* W1    = (const float*)d_in[4];
  const float* W2    = (const float*)d_in[5];
  float* out = (float*)d_out;
  int P = in_sizes[1];

  unsigned short* W1f = (unsigned short*)d_ws;                 // 32768 bf16
  unsigned short* W2f = W1f + N_IN * HID;                      // 524288 bf16

  int prep_threads = N_IN * HID + HID * N_IN * NB;             // 557056
  prep_kernel<<<(prep_threads + 255) / 256, 256, 0, stream>>>(W1, W2, W1f, W2f);

  int ntiles = (P + BM - 1) / BM;
  pilayer_kernel<<<ntiles, 256, 0, stream>>>(prop, idx_i, idx_j, basis, W1f, W2f, out, P);
}

// Round 5
// 493.264 us; speedup vs baseline: 2.3792x; 1.6210x over previous
//
#include <hip/hip_runtime.h>

#define N_IN 128
#define HID 256
#define NB 16
#define BM 128
#define HS_STRIDE 264   // bf16 row stride for H tile (16B pad -> 2-way banks only, free)
#define BS_STRIDE 17    // basis LDS stride (f32)

typedef __attribute__((ext_vector_type(8))) short s8v;   // 8 bf16 = 4 VGPRs
typedef __attribute__((ext_vector_type(4))) float f4v;   // MFMA 16x16x32 accumulator

__device__ __forceinline__ unsigned short f2bf(float f) {
  unsigned int u = __float_as_uint(f);
  u += 0x7fffu + ((u >> 16) & 1u);   // round-to-nearest-even
  return (unsigned short)(u >> 16);
}

__device__ __forceinline__ float tanh_fast(float x) {
  float e = __expf(2.0f * x);
  return 1.0f - 2.0f * __builtin_amdgcn_rcpf(e + 1.0f);
}

// Fragment-ordered bf16 repack (1 KB coalesced MFMA fragments), as round 2.
// W1f frag (pass,kk,ct): n = pass*128+ct*16+l15, k = kk*32+quad*8+j, val = W1[k*256+n]
// W2f frag (b,kk,ct):    n = ct*16+l15,          k = kk*32+quad*8+j, val = W2[k*2048+n*16+b]
__global__ void prep_kernel(const float* __restrict__ W1, const float* __restrict__ W2,
                            unsigned short* __restrict__ W1f, unsigned short* __restrict__ W2f) {
  int tid = blockIdx.x * blockDim.x + threadIdx.x;
  if (tid < N_IN * HID) {
    int j = tid & 7, lane = (tid >> 3) & 63, ct = (tid >> 9) & 7, kk = (tid >> 12) & 3, pass = tid >> 14;
    int n = pass * 128 + ct * 16 + (lane & 15);
    int k = kk * 32 + (lane >> 4) * 8 + j;
    W1f[tid] = f2bf(W1[k * HID + n]);
  }
  int i = tid - N_IN * HID;
  if (i >= 0 && i < HID * (N_IN * NB)) {
    int j = i & 7, lane = (i >> 3) & 63, ct = (i >> 9) & 7, kk = (i >> 12) & 7, b = i >> 15;
    int n = ct * 16 + (lane & 15);
    int k = kk * 32 + (lane >> 4) * 8 + j;
    W2f[i] = f2bf(W2[k * (N_IN * NB) + n * 16 + b]);
  }
}

__global__ void __launch_bounds__(256, 2)
pilayer_kernel(const float* __restrict__ prop,
               const int* __restrict__ idx_i,
               const int* __restrict__ idx_j,
               const float* __restrict__ basis,
               const unsigned short* __restrict__ W1f,
               const unsigned short* __restrict__ W2f,
               float* __restrict__ out, int P) {
  __shared__ unsigned short Hs[BM * HS_STRIDE];   // 67,584 B (live through phase C)
  __shared__ float basisS[BM * BS_STRIDE];        //  8,704 B  -> 76.3 KB, 2 blocks/CU

  const int t = threadIdx.x;
  const int lane = t & 63;
  const int wv = t >> 6;
  const int l15 = lane & 15;
  const int l4 = lane >> 4;
  const int tile0 = blockIdx.x * BM;

  // ---- stage basis tile cooperatively ----
  {
    int r = t >> 1;
    int c0 = (t & 1) * 8;
    int p = tile0 + r; if (p >= P) p = P - 1;
    const float4* bp = (const float4*)(basis + (long)p * NB + c0);
    float4 b0 = bp[0], b1 = bp[1];
    float* dst = &basisS[r * BS_STRIDE + c0];
    dst[0] = b0.x; dst[1] = b0.y; dst[2] = b0.z; dst[3] = b0.w;
    dst[4] = b1.x; dst[5] = b1.y; dst[6] = b1.z; dst[7] = b1.w;
  }

  // ---- Phase B: wave wv computes H rows [32*wv, 32*wv+32), all 256 cols (round-2 verified) ----
  {
    const int row0 = wv * 32;
    int pidx[2], qidx[2];
#pragma unroll
    for (int rt = 0; rt < 2; ++rt) {
      int p = tile0 + row0 + rt * 16 + l15; if (p >= P) p = P - 1;
      pidx[rt] = idx_i[p];
      qidx[rt] = idx_j[p];
    }
#pragma unroll
    for (int pass = 0; pass < 2; ++pass) {
      f4v acc[2][8];
#pragma unroll
      for (int rt = 0; rt < 2; ++rt)
#pragma unroll
        for (int ct = 0; ct < 8; ++ct) acc[rt][ct] = (f4v){0.f, 0.f, 0.f, 0.f};
#pragma unroll
      for (int kk = 0; kk < 4; ++kk) {
        int k0 = kk * 32 + l4 * 8;
        s8v afr[2];
#pragma unroll
        for (int rt = 0; rt < 2; ++rt) {
          const float4* ai = (const float4*)(prop + (long)pidx[rt] * N_IN + k0);
          const float4* aj = (const float4*)(prop + (long)qidx[rt] * N_IN + k0);
          float4 x0 = ai[0], x1 = ai[1];
          float4 y0 = aj[0], y1 = aj[1];
          s8v a;
          a[0] = (short)f2bf(x0.x + y0.x); a[1] = (short)f2bf(x0.y + y0.y);
          a[2] = (short)f2bf(x0.z + y0.z); a[3] = (short)f2bf(x0.w + y0.w);
          a[4] = (short)f2bf(x1.x + y1.x); a[5] = (short)f2bf(x1.y + y1.y);
          a[6] = (short)f2bf(x1.z + y1.z); a[7] = (short)f2bf(x1.w + y1.w);
          afr[rt] = a;
        }
#pragma unroll
        for (int ct = 0; ct < 8; ++ct) {
          s8v bfr = *(const s8v*)(W1f + ((((pass * 4 + kk) * 8 + ct) * 64 + lane) << 3));
#pragma unroll
          for (int rt = 0; rt < 2; ++rt)
            acc[rt][ct] = __builtin_amdgcn_mfma_f32_16x16x32_bf16(afr[rt], bfr, acc[rt][ct], 0, 0, 0);
        }
      }
#pragma unroll
      for (int rt = 0; rt < 2; ++rt)
#pragma unroll
        for (int ct = 0; ct < 8; ++ct)
#pragma unroll
          for (int r = 0; r < 4; ++r) {
            int lrow = row0 + rt * 16 + l4 * 4 + r;
            int col = pass * 128 + ct * 16 + l15;
            Hs[lrow * HS_STRIDE + col] = f2bf(tanh_fast(acc[rt][ct][r]));
          }
    }
  }

  __syncthreads();   // H + basis visible to all waves

  // ---- Phase C: 2x2 wave partition; wave (rg,cg) owns rows rg*64..+64, cols cg*64..+64.
  // A (H) cached in registers per K-half; B double-buffered in registers from global W2f.
  const int rg = wv >> 1, cg = wv & 1;
  const int rbase = rg * 64;

  f4v o[4][4];   // [rt][q] -> rows rbase+rt*16.., cols (cg*4+q)*16..
#pragma unroll
  for (int rt = 0; rt < 4; ++rt)
#pragma unroll
    for (int q = 0; q < 4; ++q) o[rt][q] = (f4v){0.f, 0.f, 0.f, 0.f};

#pragma unroll 1
  for (int khalf = 0; khalf < 2; ++khalf) {
    // A-cache: 16 fragments (64 VGPR), reused across all 16 b and 4 q
    s8v areg[4][4];   // [rt][kloc]
#pragma unroll
    for (int rt = 0; rt < 4; ++rt)
#pragma unroll
      for (int kloc = 0; kloc < 4; ++kloc)
        areg[rt][kloc] = *(const s8v*)&Hs[(rbase + rt * 16 + l15) * HS_STRIDE +
                                          (khalf * 4 + kloc) * 32 + l4 * 8];

    s8v bf[2][4];   // register double-buffer of B fragments [parity][kloc]
    // preload (b=0, q=0)
#pragma unroll
    for (int kloc = 0; kloc < 4; ++kloc)
      bf[0][kloc] = *(const s8v*)(W2f + ((((khalf * 4 + kloc) * 8) + cg * 4) << 9) + lane * 8);

#pragma unroll 1
    for (int b = 0; b < 16; ++b) {
      float bs[4][4];
#pragma unroll
      for (int rt = 0; rt < 4; ++rt)
#pragma unroll
        for (int r = 0; r < 4; ++r)
          bs[rt][r] = basisS[(rbase + rt * 16 + l4 * 4 + r) * BS_STRIDE + b];

#pragma unroll
      for (int q = 0; q < 4; ++q) {
        const int cur = q & 1;           // parity of it = b*4+q is q&1 (b*4 even) -> compile-time
        // prefetch next iteration's 4 B-fragments into the other buffer
        {
          int nb = (q == 3) ? (b + 1 < 16 ? b + 1 : 15) : b;
          int nq = (q + 1) & 3;
#pragma unroll
          for (int kloc = 0; kloc < 4; ++kloc)
            bf[cur ^ 1][kloc] = *(const s8v*)(W2f +
                (((nb * 8 + khalf * 4 + kloc) * 8 + cg * 4 + nq) << 9) + lane * 8);
        }
        f4v g[4];
#pragma unroll
        for (int rt = 0; rt < 4; ++rt) g[rt] = (f4v){0.f, 0.f, 0.f, 0.f};
#pragma unroll
        for (int kloc = 0; kloc < 4; ++kloc)
#pragma unroll
          for (int rt = 0; rt < 4; ++rt)
            g[rt] = __builtin_amdgcn_mfma_f32_16x16x32_bf16(areg[rt][kloc], bf[cur][kloc], g[rt], 0, 0, 0);
#pragma unroll
        for (int rt = 0; rt < 4; ++rt)
#pragma unroll
          for (int r = 0; r < 4; ++r)
            o[rt][q][r] += g[rt][r] * bs[rt][r];
      }
    }
  }

  // ---- epilogue: out[p][c], c = (cg*4+q)*16 + l15 ----
#pragma unroll
  for (int rt = 0; rt < 4; ++rt)
#pragma unroll
    for (int r = 0; r < 4; ++r) {
      int p = tile0 + rbase + rt * 16 + l4 * 4 + r;
      if (p < P) {
        float* op = out + (long)p * N_IN + cg * 64 + l15;
#pragma unroll
        for (int q = 0; q < 4; ++q)
          op[q * 16] = o[rt][q][r];
      }
    }
}

extern "C" void kernel_launch(void* const* d_in, const int* in_sizes, int n_in,
                              void* d_out, int out_size, void* d_ws, size_t ws_size,
                              hipStream_t stream) {
  const float* prop  = (const float*)d_in[0];
  const int* idx_i   = (const int*)d_in[1];
  const int* idx_j   = (const int*)d_in[2];
  const float* basis = (const float*)d_in[3];
  const float* W1    = (const float*)d_in[4];
  const float* W2    = (const float*)d_in[5];
  float* out = (float*)d_out;
  int P = in_sizes[1];

  unsigned short* W1f = (unsigned short*)d_ws;                 // 32768 bf16
  unsigned short* W2f = W1f + N_IN * HID;                      // 524288 bf16

  int prep_threads = N_IN * HID + HID * N_IN * NB;             // 557056
  prep_kernel<<<(prep_threads + 255) / 256, 256, 0, stream>>>(W1, W2, W1f, W2f);

  int ntiles = (P + BM - 1) / BM;
  pilayer_kernel<<<ntiles, 256, 0, stream>>>(prop, idx_i, idx_j, basis, W1f, W2f, out, P);
}